// Round 18
// baseline (46.819 us; speedup 1.0000x reference)
//
#include <hip/hip_runtime.h>
#include <hip/hip_fp16.h>

typedef _Float16 half8 __attribute__((ext_vector_type(8)));
typedef float float4v __attribute__((ext_vector_type(4)));

#define E_DIM 300
#define KP 320               // padded K (10 MFMA k-steps of 32)
#define B_ 32
#define NROW_CDD 3200        // 32*5*20
#define NROW_HIS 32000       // 32*50*20
#define NCHUNK 25            // 2 h (40 his rows) per chunk

// ---------------- Kernel 1: gather + l2-normalize -> fp16 rows (K padded to 320) --------
__global__ __launch_bounds__(256) void gather_norm(const int* __restrict__ cand,
                                                   const int* __restrict__ clk,
                                                   const float* __restrict__ emb,
                                                   _Float16* __restrict__ outH)
{
    int row  = blockIdx.x * 4 + (threadIdx.x >> 6);
    int lane = threadIdx.x & 63;
    int tok = (row < NROW_CDD) ? cand[row] : clk[row - NROW_CDD];
    const float* e = emb + (long)tok * E_DIM;
    float v[5];
    float ss = 0.f;
#pragma unroll
    for (int j = 0; j < 5; ++j) {
        int idx = lane + j * 64;
        float x = (idx < E_DIM) ? e[idx] : 0.f;
        v[j] = x;
        ss += x * x;
    }
#pragma unroll
    for (int off = 32; off; off >>= 1) ss += __shfl_xor(ss, off);
    float scale = 1.0f / fmaxf(sqrtf(ss), 1e-12f);
    _Float16* o = outH + (long)row * KP;
#pragma unroll
    for (int j = 0; j < 5; ++j) {
        int idx = lane + j * 64;
        o[idx] = (_Float16)((idx < E_DIM) ? v[j] * scale : 0.f);
    }
}

// ---------------- Kernel 2: fused hybrid GEMM + pooling, h-aligned 40-col chunks --------
// grid (25, 32) = 800 blocks, 448 threads (7 waves). Per wave: A rows 16w..16w+15 hoisted
// as af[10] regs; block stages B 40x640B to LDS (two-phase, XOR swizzle). 30 MFMA/wave.
// sim stays in LDS fp16; pool (R4 psum[20] register pattern) runs in-kernel. ~35 KB LDS.
__global__ __launch_bounds__(448, 2) void knrm_fused(const _Float16* __restrict__ wsH,
                                                     const float* __restrict__ cpad,
                                                     const float* __restrict__ hpad,
                                                     const float* __restrict__ ltr_w,
                                                     float* __restrict__ partial)
{
    __shared__ __align__(16) char Bbuf[40 * 640 + 128];   // 25.7 KB (+swizzle pad)
    __shared__ _Float16 simT[100 * 42];                   // 8.4 KB
    __shared__ float hpS[40];
    __shared__ float wvS[40];
    __shared__ float cS[100];
    __shared__ float svals[200];

    int b = blockIdx.y, chunk = blockIdx.x;               // cols chunk*40..+39 (= h 2c,2c+1)
    int tid = threadIdx.x;
    int wave = tid >> 6, lane = tid & 63;
    int g4 = lane >> 4, r16 = lane & 15;

    const char* gA = (const char*)(wsH + (size_t)b * 100 * KP);
    const char* gB = (const char*)(wsH + (size_t)(NROW_CDD + b * 1000 + chunk * 40) * KP);

    // ---- hoist A slice: 10 independent 16B loads (this wave's 16 rows) ----
    int rA = wave * 16 + r16; if (rA > 99) rA = 99;
    const char* pA = gA + (size_t)rA * 640;
    half8 af[10];
#pragma unroll
    for (int k = 0; k < 10; ++k) af[k] = *(const half8*)(pA + k * 64 + g4 * 16);

    // ---- stage B chunk: 40 rows x 640 B = 1600 uint4, two-phase hoisted ----
    uint4 bv[4];
#pragma unroll
    for (int j = 0; j < 4; ++j) {
        int u = tid + 448 * j; if (u > 1599) u = 1599;
        bv[j] = *(const uint4*)(gB + (size_t)u * 16);     // rows 0..39 within this chunk
    }
#pragma unroll
    for (int j = 0; j < 4; ++j) {
        int u = tid + 448 * j;
        if (u < 1600) {
            int r = u / 40;
            *(uint4*)(Bbuf + ((u * 16) ^ ((r & 7) << 4))) = bv[j];
        }
    }
    if (tid < 40) {
        hpS[tid] = hpad[b * 1000 + chunk * 40 + tid];
        wvS[tid] = ltr_w[chunk * 40 + tid];
    }
    if (tid >= 64 && tid < 164) cS[tid - 64] = cpad[b * 100 + (tid - 64)];
    __syncthreads();

    // ---- GEMM: 30 MFMA/wave (3 n-tiles), B from LDS, A from regs ----
    float4v acc[3];
#pragma unroll
    for (int n = 0; n < 3; ++n) acc[n] = (float4v){0.f, 0.f, 0.f, 0.f};

#pragma unroll
    for (int k = 0; k < 10; ++k) {
#pragma unroll
        for (int n = 0; n < 3; ++n) {
            int rB = n * 16 + r16; if (rB > 39) rB = 39;   // dup rows, discarded on write
            half8 bf = *(const half8*)(Bbuf + ((rB * 640 + k * 64 + g4 * 16) ^ ((rB & 7) << 4)));
            acc[n] = __builtin_amdgcn_mfma_f32_16x16x32_f16(af[k], bf, acc[n], 0, 0, 0);
        }
    }

    // C/D layout (validated r1-r17): col = lane&15 (B-row), row = (lane>>4)*4+j (A-row)
#pragma unroll
    for (int n = 0; n < 3; ++n) {
        int col = n * 16 + r16;
        if (col < 40) {
#pragma unroll
            for (int j = 0; j < 4; ++j) {
                int r = wave * 16 + g4 * 4 + j;
                if (r < 100) simT[r * 42 + col] = (_Float16)acc[n][j];
            }
        }
    }
    __syncthreads();

    // ---- pool: thread = (hl, row), psum[20] static regs, 400 exps (R4 pattern) ----
    if (tid < 200) {
        int hl = tid / 100;              // 0..1
        int row = tid - hl * 100;        // 0..99
        float psum[20];
#pragma unroll
        for (int k = 0; k < 20; ++k) psum[k] = 0.f;

        const _Float16* sp = simT + row * 42 + hl * 20;
        const float* mp = hpS + hl * 20;
#pragma unroll 4
        for (int t = 0; t < 20; ++t) {
            float s  = (float)sp[t];
            float mm = mp[t];
            float a  = -50.0f * s * s;
#pragma unroll
            for (int k = 0; k < 19; ++k) {
                const float mu = -0.9f + 0.1f * (float)k;
                float arg = fmaf(100.0f * mu, s, a - 50.0f * mu * mu);   // -50(s-mu)^2
                psum[k] = fmaf(__expf(arg), mm, psum[k]);
            }
            float d = s - 1.0f;
            psum[19] = fmaf(__expf(-500000.0f * d * d), mm, psum[19]);
        }
        float val = 0.f;
        const float* wp = wvS + hl * 20;
#pragma unroll
        for (int k = 0; k < 20; ++k)
            val += __logf(fmaxf(psum[k], 1e-10f)) * wp[k];
        svals[row * 2 + hl] = val * 0.01f * cS[row];
    }
    __syncthreads();

    // ---- per-candidate partial for this chunk ----
    if (tid < 5) {
        float ssum = 0.f;
#pragma unroll
        for (int i = 0; i < 40; ++i) ssum += svals[tid * 40 + i];
        partial[(b * 5 + tid) * NCHUNK + chunk] = ssum;
    }
}

// ---------------- Kernel 3: sum chunks + bias + log_softmax over C=5 --------------------
__global__ __launch_bounds__(64) void finalize(const float* __restrict__ partial,
                                               const float* __restrict__ ltr_b,
                                               float* __restrict__ out)
{
    int b = blockIdx.x;
    int tid = threadIdx.x;
    __shared__ float sc[5];
    if (tid < 5) {
        float a = ltr_b[0];
        const float* pp = partial + (b * 5 + tid) * NCHUNK;
#pragma unroll
        for (int ch = 0; ch < NCHUNK; ++ch) a += pp[ch];
        sc[tid] = a;
    }
    __syncthreads();
    if (tid < 5) {
        float m = fmaxf(fmaxf(fmaxf(sc[0], sc[1]), fmaxf(sc[2], sc[3])), sc[4]);
        float sum = 0.f;
#pragma unroll
        for (int i = 0; i < 5; ++i) sum += __expf(sc[i] - m);
        out[b * 5 + tid] = sc[tid] - m - __logf(sum);
    }
}

extern "C" void kernel_launch(void* const* d_in, const int* in_sizes, int n_in,
                              void* d_out, int out_size, void* d_ws, size_t ws_size,
                              hipStream_t stream)
{
    const int*   cand = (const int*)d_in[0];
    const int*   clk  = (const int*)d_in[1];
    const float* cpad = (const float*)d_in[2];
    const float* hpad = (const float*)d_in[3];
    const float* emb  = (const float*)d_in[4];
    const float* lw   = (const float*)d_in[5];
    const float* lb   = (const float*)d_in[6];
    float* out = (float*)d_out;

    _Float16* wsH  = (_Float16*)d_ws;                                                // 22.528 MB
    float* partial = (float*)((char*)d_ws + (size_t)(NROW_CDD + NROW_HIS) * KP * 2); // 16 KB

    hipLaunchKernelGGL(gather_norm, dim3((NROW_CDD + NROW_HIS) / 4), dim3(256), 0, stream,
                       cand, clk, emb, wsH);
    hipLaunchKernelGGL(knrm_fused, dim3(NCHUNK, B_), dim3(448), 0, stream,
                       wsH, cpad, hpad, lw, partial);
    hipLaunchKernelGGL(finalize, dim3(B_), dim3(64), 0, stream, partial, lb, out);
}

// Round 19
// 46.693 us; speedup vs baseline: 1.0027x; 1.0027x over previous
//
#include <hip/hip_runtime.h>
#include <hip/hip_fp16.h>

typedef _Float16 half8 __attribute__((ext_vector_type(8)));
typedef _Float16 half4v __attribute__((ext_vector_type(4)));
typedef float float4v __attribute__((ext_vector_type(4)));

#define E_DIM 300
#define KP 320               // padded K (10 MFMA k-steps of 32)
#define B_ 32
#define NROW_CDD 3200        // 32*5*20

// ---------------- Kernel 1: gather + l2-normalize CDD rows only (A side) ----------------
// grid 800, 256 threads (4 rows/block). B rows are handled raw inside sim_gemm.
__global__ __launch_bounds__(256) void gather_norm(const int* __restrict__ cand,
                                                   const float* __restrict__ emb,
                                                   _Float16* __restrict__ outH)
{
    int row  = blockIdx.x * 4 + (threadIdx.x >> 6);
    int lane = threadIdx.x & 63;
    int tok = cand[row];
    const float* e = emb + (size_t)tok * E_DIM;
    float v[5];
    float ss = 0.f;
#pragma unroll
    for (int j = 0; j < 5; ++j) {
        int idx = lane + j * 64;
        float x = (idx < E_DIM) ? e[idx] : 0.f;
        v[j] = x;
        ss += x * x;
    }
#pragma unroll
    for (int off = 32; off; off >>= 1) ss += __shfl_xor(ss, off);
    float scale = 1.0f / fmaxf(sqrtf(ss), 1e-12f);
    _Float16* o = outH + (size_t)row * KP;
#pragma unroll
    for (int j = 0; j < 5; ++j) {
        int idx = lane + j * 64;
        o[idx] = (_Float16)((idx < E_DIM) ? v[j] * scale : 0.f);
    }
}

// ---------------- Kernel 2: hybrid GEMM, A from ws (regs), B raw from emb (LDS) ---------
// grid (16, 32) = 512 blocks (2/CU, 1 round), 448 threads (7 waves).
// Stage: wave handles ~10 B-rows; per row: 75 float4 raw loads (wave-uniform token ->
// scalar addr), shfl-reduce ss -> invB, fp16 convert -> swizzled LDS, zero-pad k=300..319.
// k-loop: af[10] regs x Bbuf LDS, 40 MFMA/wave. Epilogue scales by invB[col].
__global__ __launch_bounds__(448, 2) void sim_gemm(const _Float16* __restrict__ wsA,
                                                   const int* __restrict__ clk,
                                                   const float* __restrict__ emb,
                                                   _Float16* __restrict__ simW)
{
    __shared__ __align__(16) char Bbuf[64 * 640 + 128];   // 41 KB (+swizzle guard)
    __shared__ _Float16 simT[100 * 66];                   // 13.2 KB
    __shared__ float invB[64];

    int b = blockIdx.y, ntile = blockIdx.x;               // cols ntile*64..+63
    int tid = threadIdx.x;
    int wave = tid >> 6, lane = tid & 63;
    int g4 = lane >> 4, r16 = lane & 15;

    // ---- hoist A slice: 10 independent 16B loads (normalized fp16 ws) ----
    int rA = wave * 16 + r16; if (rA > 99) rA = 99;
    const char* pA = (const char*)(wsA + (size_t)(b * 100 + rA) * KP);
    half8 af[10];
#pragma unroll
    for (int k = 0; k < 10; ++k) af[k] = *(const half8*)(pA + k * 64 + g4 * 16);

    // ---- stage B: 64 raw emb rows -> fp16 LDS + invB ----
#pragma unroll 2
    for (int i = 0; i < 10; ++i) {
        int r = wave * 10 + i;                            // 0..69; active r<64
        if (r < 64) {
            int col = ntile * 64 + r; if (col > 999) col = 999;
            int tok = clk[b * 1000 + col];                // wave-uniform -> scalar load
            const float4* e = (const float4*)(emb + (size_t)tok * E_DIM);  // 75 float4
            float4 v0 = e[lane];
            float4 v1 = {0.f, 0.f, 0.f, 0.f};
            if (lane < 11) v1 = e[64 + lane];
            float ss = v0.x*v0.x + v0.y*v0.y + v0.z*v0.z + v0.w*v0.w
                     + v1.x*v1.x + v1.y*v1.y + v1.z*v1.z + v1.w*v1.w;
#pragma unroll
            for (int o = 32; o; o >>= 1) ss += __shfl_xor(ss, o);
            if (lane == 0) invB[r] = 1.0f / fmaxf(sqrtf(ss), 1e-12f);
            int swz = (r & 7) << 4;
            half4v h0 = { (_Float16)v0.x, (_Float16)v0.y, (_Float16)v0.z, (_Float16)v0.w };
            *(half4v*)(Bbuf + ((r * 640 + lane * 8) ^ swz)) = h0;
            if (lane < 11) {
                half4v h1 = { (_Float16)v1.x, (_Float16)v1.y, (_Float16)v1.z, (_Float16)v1.w };
                *(half4v*)(Bbuf + ((r * 640 + 512 + lane * 8) ^ swz)) = h1;
            }
            if (lane < 5) {
                half4v hz = { (_Float16)0.f, (_Float16)0.f, (_Float16)0.f, (_Float16)0.f };
                *(half4v*)(Bbuf + ((r * 640 + 600 + lane * 8) ^ swz)) = hz;   // zero k 300..319
            }
        }
    }
    __syncthreads();

    // ---- k-loop: 4 ds_read_b128 + 4 MFMA per k (wave = m-tile) ----
    float4v acc[4];
#pragma unroll
    for (int n = 0; n < 4; ++n) acc[n] = (float4v){0.f, 0.f, 0.f, 0.f};

#pragma unroll
    for (int k = 0; k < 10; ++k) {
#pragma unroll
        for (int n = 0; n < 4; ++n) {
            int rB = n * 16 + r16;
            half8 bf = *(const half8*)(Bbuf + ((rB * 640 + k * 64 + g4 * 16) ^ ((rB & 7) << 4)));
            acc[n] = __builtin_amdgcn_mfma_f32_16x16x32_f16(af[k], bf, acc[n], 0, 0, 0);
        }
    }

    // C/D layout (validated r1-r18): col = lane&15 (B-row), row = (lane>>4)*4+j (A-row)
#pragma unroll
    for (int n = 0; n < 4; ++n) {
        int lcol = n * 16 + r16;
        float sc = invB[lcol];
#pragma unroll
        for (int j = 0; j < 4; ++j) {
            int r = wave * 16 + g4 * 4 + j;
            if (r < 100) simT[r * 66 + lcol] = (_Float16)(acc[n][j] * sc);
        }
    }
    __syncthreads();

    // ---- coalesced fp16 write-out: 100 rows x 64 cols ----
    for (int u = tid; u < 6400; u += 448) {
        int r = u >> 6, c = u & 63;
        int gcol = ntile * 64 + c;
        if (gcol < 1000) simW[(size_t)(b * 100 + r) * 1000 + gcol] = simT[r * 66 + c];
    }
}

// ---------------- Kernel 3: gaussian kernels + log pooling, one block per sim row -------
__global__ __launch_bounds__(256) void knrm_pool(const _Float16* __restrict__ simW,
                                                 const float* __restrict__ cpad,
                                                 const float* __restrict__ hpad,
                                                 const float* __restrict__ ltr_w,
                                                 float* __restrict__ rowsum)
{
    __shared__ float sS[50 * 21];
    __shared__ float mS[50 * 21];
    __shared__ float wS[1000];
    __shared__ float part[4];

    int row = blockIdx.x;            // (b*5+c)*20 + s
    int b = row / 100;
    int tid = threadIdx.x;

    if (tid < 250) {
        int p = tid * 4;
        half4v hv = *(const half4v*)(simW + (size_t)row * 1000 + p);
        float4v mv = *(const float4v*)(hpad + (size_t)b * 1000 + p);
        *(float4v*)&wS[p] = *(const float4v*)(ltr_w + p);
#pragma unroll
        for (int q = 0; q < 4; ++q) {
            int pq = p + q, h = pq / 20, t = pq - h * 20;
            sS[h * 21 + t] = (float)hv[q];
            mS[h * 21 + t] = mv[q];
        }
    }
    __syncthreads();

    float val = 0.f;
    if (tid < 250) {
        int h = tid % 50, kq = tid / 50;     // kq 0..4, k = kq*4+j
        float bj[4], cj[4];
        bool is19[4];
#pragma unroll
        for (int j = 0; j < 4; ++j) {
            float mu = -0.9f + 0.1f * (float)(kq * 4 + j);
            bj[j] = 100.0f * mu;
            cj[j] = -50.0f * mu * mu;
            is19[j] = (kq * 4 + j) == 19;
        }
        float psum0 = 0.f, psum1 = 0.f, psum2 = 0.f, psum3 = 0.f;
        const float* sp = sS + h * 21;
        const float* mp = mS + h * 21;
#pragma unroll 4
        for (int t = 0; t < 20; ++t) {
            float s  = sp[t];
            float mm = mp[t];
            float d  = s - 1.0f;
            float arg19 = -500000.0f * d * d;
            float a0 = is19[0] ? arg19 : fmaf(fmaf(-50.0f, s, bj[0]), s, cj[0]);
            float a1 = is19[1] ? arg19 : fmaf(fmaf(-50.0f, s, bj[1]), s, cj[1]);
            float a2 = is19[2] ? arg19 : fmaf(fmaf(-50.0f, s, bj[2]), s, cj[2]);
            float a3 = is19[3] ? arg19 : fmaf(fmaf(-50.0f, s, bj[3]), s, cj[3]);
            psum0 = fmaf(__expf(a0), mm, psum0);
            psum1 = fmaf(__expf(a1), mm, psum1);
            psum2 = fmaf(__expf(a2), mm, psum2);
            psum3 = fmaf(__expf(a3), mm, psum3);
        }
        const float* wp = wS + h * 20 + kq * 4;
        val  = __logf(fmaxf(psum0, 1e-10f)) * wp[0];
        val += __logf(fmaxf(psum1, 1e-10f)) * wp[1];
        val += __logf(fmaxf(psum2, 1e-10f)) * wp[2];
        val += __logf(fmaxf(psum3, 1e-10f)) * wp[3];
    }
#pragma unroll
    for (int off = 32; off; off >>= 1) val += __shfl_down(val, off);
    int wave = tid >> 6, lane = tid & 63;
    if (lane == 0) part[wave] = val;
    __syncthreads();
    if (tid == 0)
        rowsum[row] = (part[0] + part[1] + part[2] + part[3]) * 0.01f * cpad[row];
}

// ---------------- Kernel 4: sum rows per (b,c) + bias + log_softmax over C=5 ------------
__global__ __launch_bounds__(64) void finalize(const float* __restrict__ rowsum,
                                               const float* __restrict__ ltr_b,
                                               float* __restrict__ out)
{
    int b = blockIdx.x;
    int tid = threadIdx.x;
    __shared__ float sc[5];
    if (tid < 5) {
        float a = ltr_b[0];
        const float* rp = rowsum + (b * 5 + tid) * 20;
#pragma unroll
        for (int s = 0; s < 20; ++s) a += rp[s];
        sc[tid] = a;
    }
    __syncthreads();
    if (tid < 5) {
        float m = fmaxf(fmaxf(fmaxf(sc[0], sc[1]), fmaxf(sc[2], sc[3])), sc[4]);
        float sum = 0.f;
#pragma unroll
        for (int i = 0; i < 5; ++i) sum += __expf(sc[i] - m);
        out[b * 5 + tid] = sc[tid] - m - __logf(sum);
    }
}

extern "C" void kernel_launch(void* const* d_in, const int* in_sizes, int n_in,
                              void* d_out, int out_size, void* d_ws, size_t ws_size,
                              hipStream_t stream)
{
    const int*   cand = (const int*)d_in[0];
    const int*   clk  = (const int*)d_in[1];
    const float* cpad = (const float*)d_in[2];
    const float* hpad = (const float*)d_in[3];
    const float* emb  = (const float*)d_in[4];
    const float* lw   = (const float*)d_in[5];
    const float* lb   = (const float*)d_in[6];
    float* out = (float*)d_out;

    _Float16* wsA  = (_Float16*)d_ws;                                     // 2.048 MB
    _Float16* simW = (_Float16*)((char*)d_ws + (size_t)NROW_CDD * KP * 2);// 6.4 MB
    float* rowsum  = (float*)((char*)simW + (size_t)B_ * 100 * 1000 * 2); // 12.8 KB

    hipLaunchKernelGGL(gather_norm, dim3(NROW_CDD / 4), dim3(256), 0, stream,
                       cand, emb, wsA);
    hipLaunchKernelGGL(sim_gemm, dim3(16, B_), dim3(448), 0, stream,
                       wsA, clk, emb, simW);
    hipLaunchKernelGGL(knrm_pool, dim3(NROW_CDD), dim3(256), 0, stream,
                       simW, cpad, hpad, lw, rowsum);
    hipLaunchKernelGGL(finalize, dim3(B_), dim3(64), 0, stream, rowsum, lb, out);
}